// Round 2
// baseline (841.446 us; speedup 1.0000x reference)
//
#include <hip/hip_runtime.h>
#include <hip/hip_bf16.h>
#include <math.h>

using bf16 = __hip_bfloat16;
typedef __attribute__((ext_vector_type(8))) short short8;   // 8 bf16 (4 VGPRs)
typedef __attribute__((ext_vector_type(4))) float f32x4;    // MFMA accumulator

static __device__ __forceinline__ float b2f(bf16 x) { return __bfloat162float(x); }
static __device__ __forceinline__ bf16 f2b(float x) { return __float2bfloat16(x); }
static __device__ __forceinline__ short f2bs(float x) {
  bf16 h = __float2bfloat16(x);
  return *reinterpret_cast<short*>(&h);
}
static __device__ __forceinline__ short8 load8_f2b(const float* p) {
  float4 a = *reinterpret_cast<const float4*>(p);
  float4 b = *reinterpret_cast<const float4*>(p + 4);
  short8 r;
  r[0] = f2bs(a.x); r[1] = f2bs(a.y); r[2] = f2bs(a.z); r[3] = f2bs(a.w);
  r[4] = f2bs(b.x); r[5] = f2bs(b.y); r[6] = f2bs(b.z); r[7] = f2bs(b.w);
  return r;
}

#define MFMA16(a, b, c) __builtin_amdgcn_mfma_f32_16x16x32_bf16((a), (b), (c), 0, 0, 0)

// Problem constants
#define NB 8
#define CDIM 192
#define NTOK 16384            // 128*128
#define CN ((size_t)CDIM * NTOK)

// ---------------------------------------------------------------------------
// GEMM: OUT[o,n] = sum_c W[o,c] * X[c,n] + bias[o]
// M=192 (full), Nt=64 per block, K=192.
// mode 0: 4 projections (q1p,q2p,k1,k2) x 8 batches  (z in [0,32)), fp32 in,
//         bf16 out (proj workspace)
// mode 1: final fused GEMM, per (pair,b) bf16 weight Mbuf, fp32 X, fp32 out
// ---------------------------------------------------------------------------
struct GemmParams {
  const float *q1, *q2, *x1, *x2;
  const float *Wq, *Wk, *bq, *bk;
  bf16* proj;        // [4][8][192*16384] bf16
  const bf16* M;     // [16][192*192] bf16
  const float* Bf;   // [16][192]
  float* out;        // [16][192*16384] fp32 (= d_out)
  int mode;
};

__global__ __launch_bounds__(256, 2) void gemm_oc(GemmParams P) {
  const int tid = threadIdx.x;
  const int z = blockIdx.y;

  const float* Xf;
  const float* Wf = nullptr;   // mode 0 weights (fp32)
  const bf16* Wb = nullptr;    // mode 1 weights (bf16)
  const float* bias;
  bf16* OUTb = nullptr;
  float* OUTf = nullptr;

  if (P.mode == 0) {
    int b = z >> 2, p = z & 3;
    Xf = (p == 0 ? P.q1 : p == 1 ? P.q2 : p == 2 ? P.x1 : P.x2) + (size_t)b * CN;
    Wf = (p < 2) ? P.Wq : P.Wk;
    bias = (p < 2) ? P.bq : P.bk;
    OUTb = P.proj + (size_t)(p * 8 + b) * CN;
  } else {
    Wb = P.M + (size_t)z * (CDIM * CDIM);
    bias = P.Bf + z * CDIM;
    Xf = (((z >> 3) == 0) ? P.x2 : P.x1) + (size_t)(z & 7) * CN;
    OUTf = P.out + (size_t)z * CN;
  }

  const int n0 = blockIdx.x * 64;

  // B tile staged transposed+cast: Bs[n_loc][c], stride 200
  __shared__ __align__(16) bf16 Bs[64 * 200];
  for (int ch = tid; ch < 3072; ch += 256) {    // 192 c-rows x 16 chunks(4 fp32)
    int c = ch >> 4, jc = ch & 15;
    float4 v = *reinterpret_cast<const float4*>(Xf + (size_t)c * NTOK + n0 + jc * 4);
    Bs[(jc * 4 + 0) * 200 + c] = f2b(v.x);
    Bs[(jc * 4 + 1) * 200 + c] = f2b(v.y);
    Bs[(jc * 4 + 2) * 200 + c] = f2b(v.z);
    Bs[(jc * 4 + 3) * 200 + c] = f2b(v.w);
  }
  __syncthreads();

  const int wave = tid >> 6, lane = tid & 63;
  const int quad = lane >> 4, l15 = lane & 15;
  const int mb = wave * 48;                      // 4 waves x 48 rows = 192

  f32x4 acc[3][4];
#pragma unroll
  for (int i = 0; i < 3; i++)
#pragma unroll
    for (int j = 0; j < 4; j++) acc[i][j] = (f32x4){0.f, 0.f, 0.f, 0.f};

#pragma unroll
  for (int ks = 0; ks < 6; ks++) {
    const int k0 = ks * 32 + quad * 8;
    short8 a[3], bb[4];
#pragma unroll
    for (int mt = 0; mt < 3; mt++) {
      const int row = mb + mt * 16 + l15;
      if (P.mode == 0) a[mt] = load8_f2b(Wf + (size_t)row * CDIM + k0);
      else             a[mt] = *reinterpret_cast<const short8*>(Wb + (size_t)row * CDIM + k0);
    }
#pragma unroll
    for (int nt = 0; nt < 4; nt++)
      bb[nt] = *reinterpret_cast<const short8*>(&Bs[(nt * 16 + l15) * 200 + k0]);
#pragma unroll
    for (int mt = 0; mt < 3; mt++)
#pragma unroll
      for (int nt = 0; nt < 4; nt++) acc[mt][nt] = MFMA16(a[mt], bb[nt], acc[mt][nt]);
  }

  // epilogue: C/D layout col=lane&15, row=quad*4+reg
#pragma unroll
  for (int mt = 0; mt < 3; mt++) {
    const int obase = mb + mt * 16 + quad * 4;
    float bias4[4];
#pragma unroll
    for (int r = 0; r < 4; r++) bias4[r] = bias[obase + r];
#pragma unroll
    for (int nt = 0; nt < 4; nt++)
#pragma unroll
      for (int r = 0; r < 4; r++) {
        const size_t idx = (size_t)(obase + r) * NTOK + n0 + nt * 16 + l15;
        const float val = acc[mt][nt][r] + bias4[r];
        if (P.mode == 0) OUTb[idx] = f2b(val);
        else             OUTf[idx] = val;
      }
  }
}

// ---------------------------------------------------------------------------
// Gram: per (pair,b,h,ks): Z = [q_head(24); k_head(24)] rows, G += Z Z^T over
// K-slice. A-frag == B-frag layout -> 3 loads feed 9 MFMAs, no LDS in loop.
// ---------------------------------------------------------------------------
__global__ __launch_bounds__(256, 2) void gram48(const bf16* __restrict__ proj,
                                                 float* __restrict__ Gbuf) {
  const int blk = blockIdx.x;                 // 2*8*8*4 = 512
  const int ks = blk & 3, h = (blk >> 2) & 7, b = (blk >> 5) & 7, p = blk >> 8;

  const bf16* qsel = proj + (size_t)((p == 0 ? 0 : 1) * 8 + b) * CN + (size_t)h * 24 * NTOK;
  const bf16* ksel = proj + (size_t)((p == 0 ? 3 : 2) * 8 + b) * CN + (size_t)h * 24 * NTOK;

  const int tid = threadIdx.x, wave = tid >> 6, lane = tid & 63;
  const int quad = lane >> 4, l15 = lane & 15;

  const bf16* rp[3];
#pragma unroll
  for (int mt = 0; mt < 3; mt++) {
    int r = mt * 16 + l15;
    rp[mt] = (r < 24) ? qsel + (size_t)r * NTOK : ksel + (size_t)(r - 24) * NTOK;
  }

  f32x4 acc[3][3];
#pragma unroll
  for (int i = 0; i < 3; i++)
#pragma unroll
    for (int j = 0; j < 3; j++) acc[i][j] = (f32x4){0.f, 0.f, 0.f, 0.f};

  const int kend = ks * 4096 + 4096;
#pragma unroll 2
  for (int k = ks * 4096 + wave * 32 + quad * 8; k < kend; k += 128) {
    short8 f[3];
#pragma unroll
    for (int mt = 0; mt < 3; mt++) f[mt] = *reinterpret_cast<const short8*>(rp[mt] + k);
#pragma unroll
    for (int i = 0; i < 3; i++)
#pragma unroll
      for (int j = 0; j < 3; j++) acc[i][j] = MFMA16(f[i], f[j], acc[i][j]);
  }

  __shared__ float Gs[48 * 48];
  for (int i = tid; i < 2304; i += 256) Gs[i] = 0.f;
  __syncthreads();
#pragma unroll
  for (int i = 0; i < 3; i++)
#pragma unroll
    for (int j = 0; j < 3; j++)
#pragma unroll
      for (int r = 0; r < 4; r++)
        atomicAdd(&Gs[(i * 16 + quad * 4 + r) * 48 + j * 16 + l15], acc[i][j][r]);
  __syncthreads();

  float* gout = Gbuf + (size_t)((p * 8 + b) * 8 + h) * 2304;
  for (int i = tid; i < 2304; i += 256) atomicAdd(gout + i, Gs[i]);
}

// ---------------------------------------------------------------------------
// Softmax: A[c,d] = softmax_d( G[c][24+d] / (|q_c||k_d|) * scale[h] )
// ---------------------------------------------------------------------------
__global__ void attn_softmax(const float* __restrict__ Gbuf, const float* __restrict__ scale,
                             float* __restrict__ Abuf) {
  const int blk = blockIdx.x;               // (p*8+b)*8+h, 128 blocks
  const int h = blk & 7;
  const float* G = Gbuf + (size_t)blk * 2304;
  __shared__ float nrm[48];
  const int t = threadIdx.x;
  if (t < 48) nrm[t] = sqrtf(fmaxf(G[t * 48 + t], 0.f));
  __syncthreads();
  if (t < 24) {
    const float scl = scale[h];
    const float nq = fmaxf(nrm[t], 1e-12f);
    float lg[24], mx = -1e30f;
#pragma unroll
    for (int d = 0; d < 24; d++) {
      lg[d] = G[t * 48 + 24 + d] / (nq * fmaxf(nrm[24 + d], 1e-12f)) * scl;
      mx = fmaxf(mx, lg[d]);
    }
    float s = 0.f;
#pragma unroll
    for (int d = 0; d < 24; d++) { lg[d] = expf(lg[d] - mx); s += lg[d]; }
    const float inv = 1.f / s;
    float* Ao = Abuf + (size_t)blk * 576 + t * 24;
#pragma unroll
    for (int d = 0; d < 24; d++) Ao[d] = lg[d] * inv;
  }
}

// ---------------------------------------------------------------------------
// Fold: T[o,c'=h*24+d] = sum_cl Wproj[o, h*24+cl] A[h,cl,d]
//       M[o,e] = sum_c' T[o,c'] Wv[c',e]   (bf16 out for MFMA)
//       B[o]   = sum_c' T[o,c'] bv[c']
// grid: (pair*8+b)*12 + otile
// ---------------------------------------------------------------------------
__global__ __launch_bounds__(256) void fold_M(const float* __restrict__ Abuf,
                                              const float* __restrict__ Wproj,
                                              const float* __restrict__ Wv,
                                              const float* __restrict__ bv,
                                              bf16* __restrict__ Mbuf,
                                              float* __restrict__ Bbuf) {
  const int blk = blockIdx.x;
  const int pb = blk / 12, ot = blk % 12;
  const int tid = threadIdx.x;

  __shared__ float As[4608];          // 8 heads x 24 x 24
  __shared__ float Wps[3072];         // 16 o-rows x 192
  __shared__ float Ts[3072];          // 16 x 192
  __shared__ float bvs[192];

  for (int i = tid; i < 4608; i += 256) As[i] = Abuf[(size_t)pb * 4608 + i];
  for (int i = tid; i < 3072; i += 256)
    Wps[i] = Wproj[(size_t)(ot * 16 + i / 192) * CDIM + (i % 192)];
  if (tid < 192) bvs[tid] = bv[tid];
  __syncthreads();

  for (int idx = tid; idx < 3072; idx += 256) {
    const int tr = idx / 192, cp = idx % 192;
    const int h = cp / 24, d = cp % 24;
    const float* Ah = &As[h * 576 + d];          // A[h][cl][d], stride 24
    const float* Wr = &Wps[tr * 192 + h * 24];
    float s = 0.f;
#pragma unroll
    for (int cl = 0; cl < 24; cl++) s += Wr[cl] * Ah[cl * 24];
    Ts[idx] = s;
  }
  __syncthreads();

  for (int idx = tid; idx < 3072; idx += 256) {
    const int tr = idx / 192, e = idx % 192;
    const float* Tr = &Ts[tr * 192];
    float s = 0.f;
#pragma unroll 8
    for (int cp = 0; cp < 192; cp++) s += Tr[cp] * Wv[(size_t)cp * CDIM + e];
    Mbuf[((size_t)pb * CDIM + ot * 16 + tr) * CDIM + e] = f2b(s);
  }
  if (tid < 16) {
    const float* Tr = &Ts[tid * 192];
    float s = 0.f;
#pragma unroll 8
    for (int cp = 0; cp < 192; cp++) s += Tr[cp] * bvs[cp];
    Bbuf[pb * CDIM + ot * 16 + tid] = s;
  }
}

// ---------------------------------------------------------------------------
extern "C" void kernel_launch(void* const* d_in, const int* in_sizes, int n_in,
                              void* d_out, int out_size, void* d_ws, size_t ws_size,
                              hipStream_t stream) {
  const float* x1 = (const float*)d_in[0];
  const float* x2 = (const float*)d_in[1];
  const float* q1 = (const float*)d_in[2];
  const float* q2 = (const float*)d_in[3];
  const float* Wq = (const float*)d_in[4];
  const float* bq = (const float*)d_in[5];
  const float* Wk = (const float*)d_in[6];
  const float* bk = (const float*)d_in[7];
  const float* Wv = (const float*)d_in[8];
  const float* bv = (const float*)d_in[9];
  const float* scale = (const float*)d_in[10];
  const float* Wproj = (const float*)d_in[11];

  char* ws = (char*)d_ws;
  const size_t proj_bytes = (size_t)4 * 8 * CN * 2;        // 201,326,592
  const size_t gbuf_bytes = (size_t)2 * 8 * 8 * 2304 * 4;  // 1,179,648
  const size_t abuf_bytes = (size_t)2 * 8 * 8 * 576 * 4;   // 294,912
  const size_t mbuf_bytes = (size_t)16 * 192 * 192 * 2;    // 1,179,648

  bf16* proj = (bf16*)ws;
  float* Gbuf = (float*)(ws + proj_bytes);
  float* Abuf = (float*)(ws + proj_bytes + gbuf_bytes);
  bf16* Mbuf = (bf16*)(ws + proj_bytes + gbuf_bytes + abuf_bytes);
  float* Bbuf = (float*)(ws + proj_bytes + gbuf_bytes + abuf_bytes + mbuf_bytes);

  hipMemsetAsync(Gbuf, 0, gbuf_bytes, stream);

  GemmParams P;
  P.q1 = q1; P.q2 = q2; P.x1 = x1; P.x2 = x2;
  P.Wq = Wq; P.Wk = Wk; P.bq = bq; P.bk = bk;
  P.proj = proj; P.M = Mbuf; P.Bf = Bbuf; P.out = (float*)d_out;
  P.mode = 0;

  // K1: 4 projections x 8 batches, 256 n-tiles of 64
  gemm_oc<<<dim3(256, 32), 256, 0, stream>>>(P);
  // K2: S + norms via stacked 48x48 Gram, K split 4
  gram48<<<dim3(512), 256, 0, stream>>>(proj, Gbuf);
  // K3: softmax -> A
  attn_softmax<<<dim3(128), 64, 0, stream>>>(Gbuf, scale, Abuf);
  // K4: fold Wproj * A_blockdiag * Wv -> M, bias
  fold_M<<<dim3(192), 256, 0, stream>>>(Abuf, Wproj, Wv, bv, Mbuf, Bbuf);
  // K5: final fused GEMM -> d_out
  GemmParams P2 = P; P2.mode = 1;
  gemm_oc<<<dim3(256, 16), 256, 0, stream>>>(P2);
}